// Round 6
// baseline (200.403 us; speedup 1.0000x reference)
//
#include <hip/hip_runtime.h>
#include <math.h>

#define B_ 8
#define S_ 2048
#define F_ 1024
#define U_ 256
#define M_ (B_ * S_)   // 16384 rows

typedef __attribute__((ext_vector_type(8))) short bf16x8;
typedef __attribute__((ext_vector_type(4))) float f32x4;
typedef __attribute__((ext_vector_type(16))) float f32x16;
typedef unsigned short ushort_t;

__device__ __forceinline__ unsigned short f2bf(float x) {
    unsigned u = __builtin_bit_cast(unsigned, x);
    unsigned r = (u + 0x7fffu + ((u >> 16) & 1u)) >> 16;   // RNE
    return (unsigned short)r;
}
__device__ __forceinline__ float bf2f(unsigned short b) {
    return __builtin_bit_cast(float, ((unsigned)b) << 16);
}
__device__ __forceinline__ void gload16(const void* g, void* l) {
    __builtin_amdgcn_global_load_lds(
        (const __attribute__((address_space(1))) unsigned int*)g,
        (__attribute__((address_space(3))) unsigned int*)l, 16, 0, 0);
}
__device__ __forceinline__ f32x4 zero4() {
    f32x4 v; v[0] = 0.f; v[1] = 0.f; v[2] = 0.f; v[3] = 0.f; return v;
}

// ---------------------------------------------------------------------------
// Kernel 0: repack W fp32 [1024][256] -> bf16 hi/lo, k-slice-major:
// Wp[wsel][half][kslice=k/8][n][j=k%8].  3 MB total.  Grid (128, 3) x 256.
// This layout doubles as the direct B-FRAGMENT layout for the GEMM: lane m
// of a fragment reads 16B at element off half*262144 + kslice*2048 + n*8.
// ---------------------------------------------------------------------------
__global__ __launch_bounds__(256) void convw_kernel(
    const float* __restrict__ Wq, const float* __restrict__ Wk,
    const float* __restrict__ Wv, ushort_t* __restrict__ Wp)
{
    const int ks   = blockIdx.x;    // 0..127
    const int wsel = blockIdx.y;    // 0..2
    const float* __restrict__ W = (wsel == 0) ? Wq : (wsel == 1) ? Wk : Wv;
    const int n = threadIdx.x;      // 0..255

    bf16x8 hv, lv;
    #pragma unroll
    for (int j = 0; j < 8; ++j) {
        float v = W[(size_t)(ks * 8 + j) * U_ + n];
        ushort_t h = f2bf(v);
        hv[j] = (short)h;
        lv[j] = (short)f2bf(v - bf2f(h));
    }
    size_t base = (size_t)wsel * 524288;   // 2*128*256*8
    *reinterpret_cast<bf16x8*>(&Wp[base + ((size_t)ks) * 2048 + n * 8]) = hv;
    *reinterpret_cast<bf16x8*>(&Wp[base + ((size_t)(128 + ks)) * 2048 + n * 8]) = lv;
}

// ---------------------------------------------------------------------------
// Kernel 1: projection GEMM, split-bf16 3-pass MFMA (32x32x16).
// NEW (R6): B-fragments read DIRECTLY from global Wp (L2-resident, fragment-
// ordered layout) -- no B staging, no B LDS reads. A double-buffered in LDS
// (32 KB) with ONE __syncthreads per K-step. Block: 128 rows x 256 cols;
// 384 blocks; 4 waves (2x2), each wave 64m x 128n, acc = 2 x 4 x f32x16.
// ---------------------------------------------------------------------------
__global__ __launch_bounds__(256, 2) void proj_mfma_kernel(
    const float* __restrict__ x,
    const ushort_t* __restrict__ Wp,
    ushort_t* __restrict__ qh_g, ushort_t* __restrict__ kh_g,
    ushort_t* __restrict__ vth_g)
{
    __shared__ float As[2][128 * 32];         // [dbuf][row][chunk swz], 32 KB

    // XCD-chunked bijective swizzle over 384 = 8 x 48 blocks
    const int orig = blockIdx.y * 128 + blockIdx.x;
    const int swz  = (orig & 7) * 48 + (orig >> 3);
    const int wsel = swz >> 7;        // 128 row-tiles per weight
    const int rb   = swz & 127;
    const int row0 = rb * 128;

    const int tid = threadIdx.x;
    const int l = tid & 63, w = tid >> 6;
    const int wy = w >> 1, wx = w & 1;
    const int m = l & 31, hi = l >> 5;

    const ushort_t* __restrict__ WpB = Wp + (size_t)wsel * 524288;

    f32x16 acc[2][4];
    #pragma unroll
    for (int mr = 0; mr < 2; ++mr)
        #pragma unroll
        for (int nf = 0; nf < 4; ++nf)
            #pragma unroll
            for (int r = 0; r < 16; ++r) acc[mr][nf][r] = 0.f;

    // stage A tile for K-step ks into buffer buf (128 rows x 8 16B-chunks)
    auto stageA = [&](int buf, int ks) {
        #pragma unroll
        for (int i = 0; i < 4; ++i) {
            int q = tid + i * 256;
            int r = q >> 3, c = q & 7;
            const float* src = x + (size_t)(row0 + r) * F_ + ks * 32
                               + ((c ^ (r & 7)) << 2);
            gload16(src, (char*)&As[buf][0] + (size_t)(i * 256 + w * 64) * 16);
        }
    };

    stageA(0, 0);
    __syncthreads();   // implicit vmcnt(0) drain: A[0] visible

    for (int ks = 0; ks < 32; ++ks) {
        const int cur = ks & 1;
        if (ks < 31) stageA(cur ^ 1, ks + 1);   // lands by end-of-step barrier

        #pragma unroll
        for (int g = 0; g < 2; ++g) {
            // A-frags from LDS: row = wy*64 + mr*32 + m, k = g*16 + hi*8 + j
            bf16x8 ah[2], al[2];
            #pragma unroll
            for (int mr = 0; mr < 2; ++mr) {
                const int r  = wy * 64 + mr * 32 + m;
                const int cA = g * 4 + hi * 2;
                const float4 a0 = *reinterpret_cast<const float4*>(
                    &As[cur][(size_t)(r * 8 + (cA ^ (r & 7))) * 4]);
                const float4 a1 = *reinterpret_cast<const float4*>(
                    &As[cur][(size_t)(r * 8 + ((cA + 1) ^ (r & 7))) * 4]);
                const float af[8] = {a0.x, a0.y, a0.z, a0.w,
                                     a1.x, a1.y, a1.z, a1.w};
                #pragma unroll
                for (int j = 0; j < 8; ++j) {
                    ushort_t h = f2bf(af[j]);
                    ah[mr][j] = (short)h;
                    al[mr][j] = (short)f2bf(af[j] - bf2f(h));
                }
            }
            // B-frags DIRECT from global (L2-hit): kslice = ks*4 + g*2 + hi
            const size_t bbase = (size_t)(ks * 4 + g * 2 + hi) * 2048;
            #pragma unroll
            for (int nf = 0; nf < 4; ++nf) {
                const int nn = wx * 128 + nf * 32 + m;
                const bf16x8 bh = *reinterpret_cast<const bf16x8*>(
                    WpB + bbase + nn * 8);
                const bf16x8 bl = *reinterpret_cast<const bf16x8*>(
                    WpB + 262144 + bbase + nn * 8);
                #pragma unroll
                for (int mr = 0; mr < 2; ++mr) {
                    acc[mr][nf] = __builtin_amdgcn_mfma_f32_32x32x16_bf16(ah[mr], bh, acc[mr][nf], 0, 0, 0);
                    acc[mr][nf] = __builtin_amdgcn_mfma_f32_32x32x16_bf16(ah[mr], bl, acc[mr][nf], 0, 0, 0);
                    acc[mr][nf] = __builtin_amdgcn_mfma_f32_32x32x16_bf16(al[mr], bh, acc[mr][nf], 0, 0, 0);
                }
            }
        }
        __syncthreads();   // drains: A[next] staged, A[cur] reads done
    }

    // ---- epilogue: tanh, round to bf16, store (hi only) ----
    // C layout (32x32): col = lane&31, row = (reg&3) + 8*(reg>>2) + 4*(lane>>5)
    #pragma unroll
    for (int mr = 0; mr < 2; ++mr) {
        const int row_base = row0 + wy * 64 + mr * 32;
        if (wsel < 2) {
            ushort_t* __restrict__ hp = (wsel == 0) ? qh_g : kh_g;
            #pragma unroll
            for (int nf = 0; nf < 4; ++nf) {
                const int u = wx * 128 + nf * 32 + m;
                #pragma unroll
                for (int reg = 0; reg < 16; ++reg) {
                    const int rl = (reg & 3) + 8 * (reg >> 2) + 4 * hi;
                    hp[(size_t)(row_base + rl) * U_ + u] =
                        f2bf(tanhf(acc[mr][nf][reg]));
                }
            }
        } else {
            const int b     = row0 >> 11;    // row-tiles never straddle batches
            const int s_blk = (row0 & 2047) + wy * 64 + mr * 32;
            #pragma unroll
            for (int nf = 0; nf < 4; ++nf) {
                const int u = wx * 128 + nf * 32 + m;
                #pragma unroll
                for (int rg = 0; rg < 4; ++rg) {
                    ushort4 hv;
                    hv.x = f2bf(tanhf(acc[mr][nf][rg * 4 + 0]));
                    hv.y = f2bf(tanhf(acc[mr][nf][rg * 4 + 1]));
                    hv.z = f2bf(tanhf(acc[mr][nf][rg * 4 + 2]));
                    hv.w = f2bf(tanhf(acc[mr][nf][rg * 4 + 3]));
                    size_t off = ((size_t)b * U_ + u) * S_ + s_blk + 8 * rg + 4 * hi;
                    *reinterpret_cast<ushort4*>(&vth_g[off]) = hv;
                }
            }
        }
    }
}

// ---------------------------------------------------------------------------
// Kernel 2: flash attention, plain bf16 MFMA, SPLIT-K x2. (unchanged R5)
// ---------------------------------------------------------------------------
__global__ __launch_bounds__(256, 2) void attn_mfma_kernel(
    const ushort_t* __restrict__ qh_g,
    const ushort_t* __restrict__ kh_g,
    const ushort_t* __restrict__ vth_g,
    float* __restrict__ O0, float* __restrict__ O1,
    float* __restrict__ ml)
{
    __shared__ ushort_t Kbuf[2][32 * 256];   // [dbuf][key][u] swizzled (32 KB)
    __shared__ ushort_t Vbuf[2][256 * 40];   // [dbuf][u][32+8pad]     (40 KB)
    __shared__ ushort_t Pbuf[4][512];        // [wave][kg][q][8]        (4 KB)

    const int tid = threadIdx.x;
    const int l  = tid & 63, w = tid >> 6;
    const int kq = l & 15,  g = l >> 4;

    // XCD swizzle: each XCD owns one batch (64 blocks: 32 q-tiles x 2 halves)
    const int logical = (blockIdx.x & 7) * 64 + (blockIdx.x >> 3);
    const int b     = logical >> 6;
    const int qb    = (logical >> 1) & 31;
    const int khalf = logical & 1;
    const int qrow0 = b * S_ + qb * 64 + w * 16;
    const int kb0   = khalf * 1024;           // key offset within batch

    // preload Q fragments (B-operand: n = lane&15 -> q, k = u = g*8+j)
    bf16x8 qh[8];
    {
        const ushort_t* qbh = qh_g + (size_t)(qrow0 + kq) * U_;
        #pragma unroll
        for (int us = 0; us < 8; ++us)
            qh[us] = *reinterpret_cast<const bf16x8*>(qbh + us * 32 + g * 8);
    }

    f32x4 O[16];
    #pragma unroll
    for (int nt = 0; nt < 16; ++nt) O[nt] = zero4();
    float m_run = -INFINITY, l_run = 0.f;

    auto stage = [&](int buf, int k0) {
        #pragma unroll
        for (int i = 0; i < 4; ++i) {
            int c = w * 256 + i * 64 + l;
            int key = c >> 5, uc = c & 31;
            int ucs = uc ^ (key & 7);                       // pre-swizzled source
            size_t so = (size_t)(b * S_ + k0 + key) * U_ + ucs * 8;
            gload16(kh_g + so, &Kbuf[buf][(w * 256 + i * 64) * 8]);
        }
        #pragma unroll
        for (int i = 0; i < 5; ++i) {
            int c = w * 320 + i * 64 + l;
            int u = (c * 52429) >> 18;                      // c / 5
            int kc = c - u * 5;
            size_t so = ((size_t)b * U_ + u) * S_ + k0 + kc * 8;
            const ushort_t* sh = (kc < 4) ? (vth_g + so) : vth_g;
            gload16(sh, &Vbuf[buf][(w * 320 + i * 64) * 8]);
        }
    };

    stage(0, kb0);
    asm volatile("s_waitcnt vmcnt(0)" ::: "memory");
    __builtin_amdgcn_s_barrier();

    const float scale = 0.03125f;   // 1/sqrt(F=1024)

    for (int t = 0; t < 32; ++t) {
        const int cur = t & 1;
        if (t < 31) stage(cur ^ 1, kb0 + (t + 1) * 32);

        const ushort_t* Kh = Kbuf[cur];
        const ushort_t* Vh = Vbuf[cur];

        // ---- QK^T as S^T = K * Q^T ----
        f32x4 hh0 = zero4(), hh1 = zero4();
        #pragma unroll
        for (int us = 0; us < 8; ++us) {
            int off0 = kq * 256 + ((us * 32 + g * 8) ^ ((kq & 7) * 8));
            bf16x8 k0h = *reinterpret_cast<const bf16x8*>(Kh + off0);
            hh0 = __builtin_amdgcn_mfma_f32_16x16x32_bf16(k0h, qh[us], hh0, 0, 0, 0);
            int off1 = off0 + 16 * 256;                     // key+16
            bf16x8 k1h = *reinterpret_cast<const bf16x8*>(Kh + off1);
            hh1 = __builtin_amdgcn_mfma_f32_16x16x32_bf16(k1h, qh[us], hh1, 0, 0, 0);
        }
        f32x4 s0 = hh0 * scale;   // keys g*4+r,    q = kq
        f32x4 s1 = hh1 * scale;   // keys 16+g*4+r, q = kq

        // ---- online softmax (per q = lane&15) ----
        float tm = fmaxf(fmaxf(fmaxf(s0[0], s0[1]), fmaxf(s0[2], s0[3])),
                         fmaxf(fmaxf(s1[0], s1[1]), fmaxf(s1[2], s1[3])));
        tm = fmaxf(tm, __shfl_xor(tm, 16));
        tm = fmaxf(tm, __shfl_xor(tm, 32));
        float mn = fmaxf(m_run, tm);
        ushort_t ph0[4], ph1[4];
        float su = 0.f;
        #pragma unroll
        for (int r = 0; r < 4; ++r) {
            ph0[r] = f2bf(expf(s0[r] - mn)); su += bf2f(ph0[r]);
        }
        #pragma unroll
        for (int r = 0; r < 4; ++r) {
            ph1[r] = f2bf(expf(s1[r] - mn)); su += bf2f(ph1[r]);
        }
        su += __shfl_xor(su, 16);
        su += __shfl_xor(su, 32);
        float f = expf(m_run - mn);             // first tile: exp(-inf) = 0
        l_run = l_run * f + su;
        m_run = mn;

        // ---- write P into PV-A-fragment layout [kg][q][8] ----
        {
            ushort4 a, c;
            a.x = ph0[0]; a.y = ph0[1]; a.z = ph0[2]; a.w = ph0[3];
            c.x = ph1[0]; c.y = ph1[1]; c.z = ph1[2]; c.w = ph1[3];
            int pw0 = ((g >> 1)) * 128 + kq * 8 + (g & 1) * 4;        // kg 0|1
            int pw1 = (2 + (g >> 1)) * 128 + kq * 8 + (g & 1) * 4;    // kg 2|3
            *reinterpret_cast<ushort4*>(&Pbuf[w][pw0]) = a;
            *reinterpret_cast<ushort4*>(&Pbuf[w][pw1]) = c;
        }

        // ---- rescale O (rows of C-layout are q = g*4+r) ----
        float fr0 = __shfl(f, g * 4 + 0), fr1 = __shfl(f, g * 4 + 1);
        float fr2 = __shfl(f, g * 4 + 2), fr3 = __shfl(f, g * 4 + 3);
        #pragma unroll
        for (int nt = 0; nt < 16; ++nt) {
            O[nt][0] *= fr0; O[nt][1] *= fr1; O[nt][2] *= fr2; O[nt][3] *= fr3;
        }

        // ---- PV: O += P * V ----
        bf16x8 pa_h = *reinterpret_cast<const bf16x8*>(&Pbuf[w][g * 128 + kq * 8]);
        #pragma unroll
        for (int nt = 0; nt < 16; ++nt) {
            int vo = (nt * 16 + kq) * 40 + g * 8;
            bf16x8 vh = *reinterpret_cast<const bf16x8*>(Vh + vo);
            O[nt] = __builtin_amdgcn_mfma_f32_16x16x32_bf16(pa_h, vh, O[nt], 0, 0, 0);
        }

        asm volatile("s_waitcnt vmcnt(0)" ::: "memory");
        __builtin_amdgcn_s_barrier();
    }

    // ---- epilogue: store UNNORMALIZED O + (m, l) per row ----
    float* __restrict__ Op = khalf ? O1 : O0;
    #pragma unroll
    for (int nt = 0; nt < 16; ++nt) {
        const int col = nt * 16 + kq;
        Op[(size_t)(qrow0 + g * 4 + 0) * U_ + col] = O[nt][0];
        Op[(size_t)(qrow0 + g * 4 + 1) * U_ + col] = O[nt][1];
        Op[(size_t)(qrow0 + g * 4 + 2) * U_ + col] = O[nt][2];
        Op[(size_t)(qrow0 + g * 4 + 3) * U_ + col] = O[nt][3];
    }
    if (g == 0) {   // lanes 0..15: one per q-row of this wave
        ml[((size_t)khalf * M_ + qrow0 + kq) * 2 + 0] = m_run;
        ml[((size_t)khalf * M_ + qrow0 + kq) * 2 + 1] = l_run;
    }
}

// ---------------------------------------------------------------------------
// Kernel 3: merge the two split-K partials. (unchanged R5)
// ---------------------------------------------------------------------------
__global__ __launch_bounds__(256) void merge_kernel(
    const float* __restrict__ O1, const float* __restrict__ ml,
    float* __restrict__ out)
{
    const int tid = threadIdx.x;
    const int row = blockIdx.x * 4 + (tid >> 6);
    const int c   = (tid & 63) * 4;

    const float m0 = ml[(size_t)row * 2 + 0];
    const float l0 = ml[(size_t)row * 2 + 1];
    const float m1 = ml[((size_t)M_ + row) * 2 + 0];
    const float l1 = ml[((size_t)M_ + row) * 2 + 1];
    const float Mx = fmaxf(m0, m1);
    float a0 = expf(m0 - Mx), a1 = expf(m1 - Mx);
    const float inv = 1.f / (a0 * l0 + a1 * l1);
    a0 *= inv; a1 *= inv;

    const size_t off = (size_t)row * U_ + c;
    const float4 o0 = *reinterpret_cast<const float4*>(out + off);
    const float4 o1 = *reinterpret_cast<const float4*>(O1 + off);
    float4 r;
    r.x = o0.x * a0 + o1.x * a1;
    r.y = o0.y * a0 + o1.y * a1;
    r.z = o0.z * a0 + o1.z * a1;
    r.w = o0.w * a0 + o1.w * a1;
    *reinterpret_cast<float4*>(out + off) = r;
}

extern "C" void kernel_launch(void* const* d_in, const int* in_sizes, int n_in,
                              void* d_out, int out_size, void* d_ws, size_t ws_size,
                              hipStream_t stream)
{
    (void)in_sizes; (void)n_in; (void)out_size; (void)ws_size;
    const float* x  = (const float*)d_in[0];
    const float* Wq = (const float*)d_in[1];
    const float* Wk = (const float*)d_in[2];
    const float* Wv = (const float*)d_in[3];
    float* out = (float*)d_out;

    ushort_t* ws = (ushort_t*)d_ws;
    const size_t T = (size_t)M_ * U_;        // 4,194,304 elements
    ushort_t* qh_g  = ws;                    //  8 MiB
    ushort_t* kh_g  = ws + T;                //  8 MiB
    ushort_t* vth_g = ws + 2 * T;            //  8 MiB  [B][U][S]
    ushort_t* Wp    = ws + 3 * T;            //  3 MiB  [3][2][128][256][8]
    float*    O1    = (float*)(ws + 3 * T + 1572864);   // 16.8 MiB partial
    float*    ml    = O1 + T;                // 0.26 MiB [2][M][2]

    convw_kernel<<<dim3(128, 3), 256, 0, stream>>>(Wq, Wk, Wv, Wp);

    proj_mfma_kernel<<<dim3(128, 3), 256, 0, stream>>>(
        x, Wp, qh_g, kh_g, vth_g);

    attn_mfma_kernel<<<dim3(512), 256, 0, stream>>>(
        qh_g, kh_g, vth_g, out, O1, ml);

    merge_kernel<<<dim3(M_ / 4), 256, 0, stream>>>(O1, ml, out);
}

// Round 7
// 181.751 us; speedup vs baseline: 1.1026x; 1.1026x over previous
//
#include <hip/hip_runtime.h>
#include <math.h>

#define B_ 8
#define S_ 2048
#define F_ 1024
#define U_ 256
#define M_ (B_ * S_)   // 16384 rows

typedef __attribute__((ext_vector_type(8))) short bf16x8;
typedef __attribute__((ext_vector_type(4))) float f32x4;
typedef __attribute__((ext_vector_type(16))) float f32x16;
typedef unsigned short ushort_t;

__device__ __forceinline__ unsigned short f2bf(float x) {
    unsigned u = __builtin_bit_cast(unsigned, x);
    unsigned r = (u + 0x7fffu + ((u >> 16) & 1u)) >> 16;   // RNE
    return (unsigned short)r;
}
__device__ __forceinline__ float bf2f(unsigned short b) {
    return __builtin_bit_cast(float, ((unsigned)b) << 16);
}
__device__ __forceinline__ void gload16(const void* g, void* l) {
    __builtin_amdgcn_global_load_lds(
        (const __attribute__((address_space(1))) unsigned int*)g,
        (__attribute__((address_space(3))) unsigned int*)l, 16, 0, 0);
}
__device__ __forceinline__ f32x4 zero4() {
    f32x4 v; v[0] = 0.f; v[1] = 0.f; v[2] = 0.f; v[3] = 0.f; return v;
}

// ---------------------------------------------------------------------------
// Kernel 0: repack W fp32 [1024][256] -> bf16 hi/lo, k-slice-major:
// Wp[wsel][half][kslice=k/8][n][j=k%8].  3 MB total.  Grid (128, 3) x 256.
// ---------------------------------------------------------------------------
__global__ __launch_bounds__(256) void convw_kernel(
    const float* __restrict__ Wq, const float* __restrict__ Wk,
    const float* __restrict__ Wv, ushort_t* __restrict__ Wp)
{
    const int ks   = blockIdx.x;    // 0..127
    const int wsel = blockIdx.y;    // 0..2
    const float* __restrict__ W = (wsel == 0) ? Wq : (wsel == 1) ? Wk : Wv;
    const int n = threadIdx.x;      // 0..255

    bf16x8 hv, lv;
    #pragma unroll
    for (int j = 0; j < 8; ++j) {
        float v = W[(size_t)(ks * 8 + j) * U_ + n];
        ushort_t h = f2bf(v);
        hv[j] = (short)h;
        lv[j] = (short)f2bf(v - bf2f(h));
    }
    size_t base = (size_t)wsel * 524288;   // 2*128*256*8
    *reinterpret_cast<bf16x8*>(&Wp[base + ((size_t)ks) * 2048 + n * 8]) = hv;
    *reinterpret_cast<bf16x8*>(&Wp[base + ((size_t)(128 + ks)) * 2048 + n * 8]) = lv;
}

// ---------------------------------------------------------------------------
// Kernel 1 (R7): projection GEMM, 2-PASS split-bf16 MFMA (32x32x16):
// z = bf16(x) * (W_hi + W_lo).  BK=16, 64 K-steps, both A and B double-
// buffered in LDS (48 KB -> 2 blocks/CU). 4 waves, each 128m x 64n,
// acc = 4mr x 2nf x f32x16. 12 ds_read_b128/wave/K-step, all <=2-way banked.
// Grid 384: XCD-grouped so the 3 weights of one row-tile share the x tile
// in that XCD's L2 (x HBM traffic ~1x instead of 3x).
// ---------------------------------------------------------------------------
__global__ __launch_bounds__(256, 2) void proj_mfma_kernel(
    const float* __restrict__ x,
    const ushort_t* __restrict__ Wp,
    ushort_t* __restrict__ qh_g, ushort_t* __restrict__ kh_g,
    ushort_t* __restrict__ vth_g)
{
    __shared__ float    As[2][128 * 16];        // 2 x 8 KB  [row][chunk swz]
    __shared__ ushort_t Bs[2][2 * 2 * 256 * 8]; // 2 x 16 KB [half][ksl][n][8]

    // XCD grouping: xcd = orig&7 owns row-tiles xcd*16..+15; the 3 wsel
    // blocks of a row-tile are consecutive within the XCD.
    const int orig = blockIdx.x;            // 0..383
    const int xcd  = orig & 7;
    const int idx  = orig >> 3;             // 0..47
    const int q3   = idx / 3;
    const int wsel = idx - q3 * 3;
    const int rt   = xcd * 16 + q3;         // 0..127
    const int row0 = rt * 128;

    const int tid = threadIdx.x;
    const int l = tid & 63, w = tid >> 6;   // w = n-quarter (wx)
    const int m = l & 31, hi = l >> 5;

    const ushort_t* __restrict__ WpB = Wp + (size_t)wsel * 524288;

    f32x16 acc[4][2];
    #pragma unroll
    for (int mr = 0; mr < 4; ++mr)
        #pragma unroll
        for (int nf = 0; nf < 2; ++nf)
            #pragma unroll
            for (int r = 0; r < 16; ++r) acc[mr][nf][r] = 0.f;

    // stage A tile (128 rows x 16 k fp32 = 512 chunks), XOR-preswizzled src
    auto stageA = [&](int buf, int ks) {
        #pragma unroll
        for (int i = 0; i < 2; ++i) {
            int c = i * 256 + tid;              // LDS chunk index
            int r = c >> 2, cc = c & 3;
            int cs = cc ^ ((r + (r >> 2)) & 3); // logical chunk at this slot
            const float* src = x + (size_t)(row0 + r) * F_ + ks * 16 + cs * 4;
            gload16(src, (char*)&As[buf][0] + (size_t)(i * 256 + w * 64) * 16);
        }
    };
    // stage B: both halves' 2 kslices (16 KB = 1024 chunks), pure linear
    auto stageB = [&](int buf, int ks) {
        #pragma unroll
        for (int i = 0; i < 4; ++i) {
            int c = i * 256 + tid;
            int half = c >> 9, rem = c & 511;
            size_t so = (size_t)half * 262144 + (size_t)ks * 4096 + rem * 8;
            gload16(WpB + so, (char*)&Bs[buf][0] + (size_t)(i * 256 + w * 64) * 16);
        }
    };

    stageA(0, 0);
    stageB(0, 0);
    __syncthreads();   // implicit vmcnt(0) drain

    for (int ks = 0; ks < 64; ++ks) {
        const int cur = ks & 1;
        if (ks < 63) { stageA(cur ^ 1, ks + 1); stageB(cur ^ 1, ks + 1); }

        const float*    Ac = &As[cur][0];
        const ushort_t* Bc = &Bs[cur][0];

        // A-frags: row = mr*32+m, k = hi*8+j  (fp32 chunks 2hi, 2hi+1)
        bf16x8 ah[4];
        #pragma unroll
        for (int mr = 0; mr < 4; ++mr) {
            const int r   = mr * 32 + m;
            const int swz = (r + (r >> 2)) & 3;
            const float4 a0 = *reinterpret_cast<const float4*>(
                &Ac[(size_t)(r * 4 + ((2 * hi) ^ swz)) * 4]);
            const float4 a1 = *reinterpret_cast<const float4*>(
                &Ac[(size_t)(r * 4 + ((2 * hi + 1) ^ swz)) * 4]);
            const float af[8] = {a0.x, a0.y, a0.z, a0.w, a1.x, a1.y, a1.z, a1.w};
            #pragma unroll
            for (int j = 0; j < 8; ++j) ah[mr][j] = (short)f2bf(af[j]);
        }
        // B-frags: n = w*64 + nf*32 + m, kslice_local = hi; hi+lo halves
        #pragma unroll
        for (int nf = 0; nf < 2; ++nf) {
            const int nn = w * 64 + nf * 32 + m;
            const bf16x8 bh = *reinterpret_cast<const bf16x8*>(
                &Bc[(size_t)(hi * 2048 + nn * 8)]);
            const bf16x8 bl = *reinterpret_cast<const bf16x8*>(
                &Bc[(size_t)(4096 + hi * 2048 + nn * 8)]);
            #pragma unroll
            for (int mr = 0; mr < 4; ++mr) {
                acc[mr][nf] = __builtin_amdgcn_mfma_f32_32x32x16_bf16(ah[mr], bh, acc[mr][nf], 0, 0, 0);
                acc[mr][nf] = __builtin_amdgcn_mfma_f32_32x32x16_bf16(ah[mr], bl, acc[mr][nf], 0, 0, 0);
            }
        }
        __syncthreads();   // next-buf staged, cur-buf reads done
    }

    // ---- epilogue: tanh, round to bf16, store (hi only) ----
    // C layout (32x32): col = lane&31, row = (reg&3) + 8*(reg>>2) + 4*(lane>>5)
    #pragma unroll
    for (int mr = 0; mr < 4; ++mr) {
        const int row_base = row0 + mr * 32;
        if (wsel < 2) {
            ushort_t* __restrict__ hp = (wsel == 0) ? qh_g : kh_g;
            #pragma unroll
            for (int nf = 0; nf < 2; ++nf) {
                const int u = w * 64 + nf * 32 + m;
                #pragma unroll
                for (int reg = 0; reg < 16; ++reg) {
                    const int rl = (reg & 3) + 8 * (reg >> 2) + 4 * hi;
                    hp[(size_t)(row_base + rl) * U_ + u] =
                        f2bf(tanhf(acc[mr][nf][reg]));
                }
            }
        } else {
            const int b     = row0 >> 11;    // row-tiles never straddle batches
            const int s_blk = (row0 & 2047) + mr * 32;
            #pragma unroll
            for (int nf = 0; nf < 2; ++nf) {
                const int u = w * 64 + nf * 32 + m;
                #pragma unroll
                for (int rg = 0; rg < 4; ++rg) {
                    ushort4 hv;
                    hv.x = f2bf(tanhf(acc[mr][nf][rg * 4 + 0]));
                    hv.y = f2bf(tanhf(acc[mr][nf][rg * 4 + 1]));
                    hv.z = f2bf(tanhf(acc[mr][nf][rg * 4 + 2]));
                    hv.w = f2bf(tanhf(acc[mr][nf][rg * 4 + 3]));
                    size_t off = ((size_t)b * U_ + u) * S_ + s_blk + 8 * rg + 4 * hi;
                    *reinterpret_cast<ushort4*>(&vth_g[off]) = hv;
                }
            }
        }
    }
}

// ---------------------------------------------------------------------------
// Kernel 2: flash attention, plain bf16 MFMA, SPLIT-K x2. (unchanged R5)
// ---------------------------------------------------------------------------
__global__ __launch_bounds__(256, 2) void attn_mfma_kernel(
    const ushort_t* __restrict__ qh_g,
    const ushort_t* __restrict__ kh_g,
    const ushort_t* __restrict__ vth_g,
    float* __restrict__ O0, float* __restrict__ O1,
    float* __restrict__ ml)
{
    __shared__ ushort_t Kbuf[2][32 * 256];   // [dbuf][key][u] swizzled (32 KB)
    __shared__ ushort_t Vbuf[2][256 * 40];   // [dbuf][u][32+8pad]     (40 KB)
    __shared__ ushort_t Pbuf[4][512];        // [wave][kg][q][8]        (4 KB)

    const int tid = threadIdx.x;
    const int l  = tid & 63, w = tid >> 6;
    const int kq = l & 15,  g = l >> 4;

    // XCD swizzle: each XCD owns one batch (64 blocks: 32 q-tiles x 2 halves)
    const int logical = (blockIdx.x & 7) * 64 + (blockIdx.x >> 3);
    const int b     = logical >> 6;
    const int qb    = (logical >> 1) & 31;
    const int khalf = logical & 1;
    const int qrow0 = b * S_ + qb * 64 + w * 16;
    const int kb0   = khalf * 1024;           // key offset within batch

    // preload Q fragments (B-operand: n = lane&15 -> q, k = u = g*8+j)
    bf16x8 qh[8];
    {
        const ushort_t* qbh = qh_g + (size_t)(qrow0 + kq) * U_;
        #pragma unroll
        for (int us = 0; us < 8; ++us)
            qh[us] = *reinterpret_cast<const bf16x8*>(qbh + us * 32 + g * 8);
    }

    f32x4 O[16];
    #pragma unroll
    for (int nt = 0; nt < 16; ++nt) O[nt] = zero4();
    float m_run = -INFINITY, l_run = 0.f;

    auto stage = [&](int buf, int k0) {
        #pragma unroll
        for (int i = 0; i < 4; ++i) {
            int c = w * 256 + i * 64 + l;
            int key = c >> 5, uc = c & 31;
            int ucs = uc ^ (key & 7);                       // pre-swizzled source
            size_t so = (size_t)(b * S_ + k0 + key) * U_ + ucs * 8;
            gload16(kh_g + so, &Kbuf[buf][(w * 256 + i * 64) * 8]);
        }
        #pragma unroll
        for (int i = 0; i < 5; ++i) {
            int c = w * 320 + i * 64 + l;
            int u = (c * 52429) >> 18;                      // c / 5
            int kc = c - u * 5;
            size_t so = ((size_t)b * U_ + u) * S_ + k0 + kc * 8;
            const ushort_t* sh = (kc < 4) ? (vth_g + so) : vth_g;
            gload16(sh, &Vbuf[buf][(w * 320 + i * 64) * 8]);
        }
    };

    stage(0, kb0);
    asm volatile("s_waitcnt vmcnt(0)" ::: "memory");
    __builtin_amdgcn_s_barrier();

    const float scale = 0.03125f;   // 1/sqrt(F=1024)

    for (int t = 0; t < 32; ++t) {
        const int cur = t & 1;
        if (t < 31) stage(cur ^ 1, kb0 + (t + 1) * 32);

        const ushort_t* Kh = Kbuf[cur];
        const ushort_t* Vh = Vbuf[cur];

        // ---- QK^T as S^T = K * Q^T ----
        f32x4 hh0 = zero4(), hh1 = zero4();
        #pragma unroll
        for (int us = 0; us < 8; ++us) {
            int off0 = kq * 256 + ((us * 32 + g * 8) ^ ((kq & 7) * 8));
            bf16x8 k0h = *reinterpret_cast<const bf16x8*>(Kh + off0);
            hh0 = __builtin_amdgcn_mfma_f32_16x16x32_bf16(k0h, qh[us], hh0, 0, 0, 0);
            int off1 = off0 + 16 * 256;                     // key+16
            bf16x8 k1h = *reinterpret_cast<const bf16x8*>(Kh + off1);
            hh1 = __builtin_amdgcn_mfma_f32_16x16x32_bf16(k1h, qh[us], hh1, 0, 0, 0);
        }
        f32x4 s0 = hh0 * scale;   // keys g*4+r,    q = kq
        f32x4 s1 = hh1 * scale;   // keys 16+g*4+r, q = kq

        // ---- online softmax (per q = lane&15) ----
        float tm = fmaxf(fmaxf(fmaxf(s0[0], s0[1]), fmaxf(s0[2], s0[3])),
                         fmaxf(fmaxf(s1[0], s1[1]), fmaxf(s1[2], s1[3])));
        tm = fmaxf(tm, __shfl_xor(tm, 16));
        tm = fmaxf(tm, __shfl_xor(tm, 32));
        float mn = fmaxf(m_run, tm);
        ushort_t ph0[4], ph1[4];
        float su = 0.f;
        #pragma unroll
        for (int r = 0; r < 4; ++r) {
            ph0[r] = f2bf(expf(s0[r] - mn)); su += bf2f(ph0[r]);
        }
        #pragma unroll
        for (int r = 0; r < 4; ++r) {
            ph1[r] = f2bf(expf(s1[r] - mn)); su += bf2f(ph1[r]);
        }
        su += __shfl_xor(su, 16);
        su += __shfl_xor(su, 32);
        float f = expf(m_run - mn);             // first tile: exp(-inf) = 0
        l_run = l_run * f + su;
        m_run = mn;

        // ---- write P into PV-A-fragment layout [kg][q][8] ----
        {
            ushort4 a, c;
            a.x = ph0[0]; a.y = ph0[1]; a.z = ph0[2]; a.w = ph0[3];
            c.x = ph1[0]; c.y = ph1[1]; c.z = ph1[2]; c.w = ph1[3];
            int pw0 = ((g >> 1)) * 128 + kq * 8 + (g & 1) * 4;        // kg 0|1
            int pw1 = (2 + (g >> 1)) * 128 + kq * 8 + (g & 1) * 4;    // kg 2|3
            *reinterpret_cast<ushort4*>(&Pbuf[w][pw0]) = a;
            *reinterpret_cast<ushort4*>(&Pbuf[w][pw1]) = c;
        }

        // ---- rescale O (rows of C-layout are q = g*4+r) ----
        float fr0 = __shfl(f, g * 4 + 0), fr1 = __shfl(f, g * 4 + 1);
        float fr2 = __shfl(f, g * 4 + 2), fr3 = __shfl(f, g * 4 + 3);
        #pragma unroll
        for (int nt = 0; nt < 16; ++nt) {
            O[nt][0] *= fr0; O[nt][1] *= fr1; O[nt][2] *= fr2; O[nt][3] *= fr3;
        }

        // ---- PV: O += P * V ----
        bf16x8 pa_h = *reinterpret_cast<const bf16x8*>(&Pbuf[w][g * 128 + kq * 8]);
        #pragma unroll
        for (int nt = 0; nt < 16; ++nt) {
            int vo = (nt * 16 + kq) * 40 + g * 8;
            bf16x8 vh = *reinterpret_cast<const bf16x8*>(Vh + vo);
            O[nt] = __builtin_amdgcn_mfma_f32_16x16x32_bf16(pa_h, vh, O[nt], 0, 0, 0);
        }

        asm volatile("s_waitcnt vmcnt(0)" ::: "memory");
        __builtin_amdgcn_s_barrier();
    }

    // ---- epilogue: store UNNORMALIZED O + (m, l) per row ----
    float* __restrict__ Op = khalf ? O1 : O0;
    #pragma unroll
    for (int nt = 0; nt < 16; ++nt) {
        const int col = nt * 16 + kq;
        Op[(size_t)(qrow0 + g * 4 + 0) * U_ + col] = O[nt][0];
        Op[(size_t)(qrow0 + g * 4 + 1) * U_ + col] = O[nt][1];
        Op[(size_t)(qrow0 + g * 4 + 2) * U_ + col] = O[nt][2];
        Op[(size_t)(qrow0 + g * 4 + 3) * U_ + col] = O[nt][3];
    }
    if (g == 0) {   // lanes 0..15: one per q-row of this wave
        ml[((size_t)khalf * M_ + qrow0 + kq) * 2 + 0] = m_run;
        ml[((size_t)khalf * M_ + qrow0 + kq) * 2 + 1] = l_run;
    }
}

// ---------------------------------------------------------------------------
// Kernel 3: merge the two split-K partials. (unchanged R5)
// ---------------------------------------------------------------------------
__global__ __launch_bounds__(256) void merge_kernel(
    const float* __restrict__ O1, const float* __restrict__ ml,
    float* __restrict__ out)
{
    const int tid = threadIdx.x;
    const int row = blockIdx.x * 4 + (tid >> 6);
    const int c   = (tid & 63) * 4;

    const float m0 = ml[(size_t)row * 2 + 0];
    const float l0 = ml[(size_t)row * 2 + 1];
    const float m1 = ml[((size_t)M_ + row) * 2 + 0];
    const float l1 = ml[((size_t)M_ + row) * 2 + 1];
    const float Mx = fmaxf(m0, m1);
    float a0 = expf(m0 - Mx), a1 = expf(m1 - Mx);
    const float inv = 1.f / (a0 * l0 + a1 * l1);
    a0 *= inv; a1 *= inv;

    const size_t off = (size_t)row * U_ + c;
    const float4 o0 = *reinterpret_cast<const float4*>(out + off);
    const float4 o1 = *reinterpret_cast<const float4*>(O1 + off);
    float4 r;
    r.x = o0.x * a0 + o1.x * a1;
    r.y = o0.y * a0 + o1.y * a1;
    r.z = o0.z * a0 + o1.z * a1;
    r.w = o0.w * a0 + o1.w * a1;
    *reinterpret_cast<float4*>(out + off) = r;
}

extern "C" void kernel_launch(void* const* d_in, const int* in_sizes, int n_in,
                              void* d_out, int out_size, void* d_ws, size_t ws_size,
                              hipStream_t stream)
{
    (void)in_sizes; (void)n_in; (void)out_size; (void)ws_size;
    const float* x  = (const float*)d_in[0];
    const float* Wq = (const float*)d_in[1];
    const float* Wk = (const float*)d_in[2];
    const float* Wv = (const float*)d_in[3];
    float* out = (float*)d_out;

    ushort_t* ws = (ushort_t*)d_ws;
    const size_t T = (size_t)M_ * U_;        // 4,194,304 elements
    ushort_t* qh_g  = ws;                    //  8 MiB
    ushort_t* kh_g  = ws + T;                //  8 MiB
    ushort_t* vth_g = ws + 2 * T;            //  8 MiB  [B][U][S]
    ushort_t* Wp    = ws + 3 * T;            //  3 MiB  [3][2][128][256][8]
    float*    O1    = (float*)(ws + 3 * T + 1572864);   // 16.8 MiB partial
    float*    ml    = O1 + T;                // 0.26 MiB [2][M][2]

    convw_kernel<<<dim3(128, 3), 256, 0, stream>>>(Wq, Wk, Wv, Wp);

    proj_mfma_kernel<<<dim3(384), 256, 0, stream>>>(
        x, Wp, qh_g, kh_g, vth_g);

    attn_mfma_kernel<<<dim3(512), 256, 0, stream>>>(
        qh_g, kh_g, vth_g, out, O1, ml);

    merge_kernel<<<dim3(M_ / 4), 256, 0, stream>>>(O1, ml, out);
}

// Round 8
// 179.037 us; speedup vs baseline: 1.1193x; 1.0152x over previous
//
#include <hip/hip_runtime.h>
#include <math.h>

#define B_ 8
#define S_ 2048
#define F_ 1024
#define U_ 256
#define M_ (B_ * S_)   // 16384 rows

typedef __attribute__((ext_vector_type(8))) short bf16x8;
typedef __attribute__((ext_vector_type(4))) float f32x4;
typedef __attribute__((ext_vector_type(16))) float f32x16;
typedef unsigned short ushort_t;

__device__ __forceinline__ unsigned short f2bf(float x) {
    unsigned u = __builtin_bit_cast(unsigned, x);
    unsigned r = (u + 0x7fffu + ((u >> 16) & 1u)) >> 16;   // RNE
    return (unsigned short)r;
}
__device__ __forceinline__ float bf2f(unsigned short b) {
    return __builtin_bit_cast(float, ((unsigned)b) << 16);
}
__device__ __forceinline__ void gload16(const void* g, void* l) {
    __builtin_amdgcn_global_load_lds(
        (const __attribute__((address_space(1))) unsigned int*)g,
        (__attribute__((address_space(3))) unsigned int*)l, 16, 0, 0);
}
__device__ __forceinline__ f32x4 zero4() {
    f32x4 v; v[0] = 0.f; v[1] = 0.f; v[2] = 0.f; v[3] = 0.f; return v;
}

// ---------------------------------------------------------------------------
// Kernel 0a: x fp32 [M][F] -> bf16 xb [M][F] (RNE). Pure BW (96 MB).
// 4096 blocks x 256 thr x 16 elem.
// ---------------------------------------------------------------------------
__global__ __launch_bounds__(256) void convx_kernel(
    const float* __restrict__ x, ushort_t* __restrict__ xb)
{
    const size_t base = ((size_t)blockIdx.x * 256 + threadIdx.x) * 16;
    #pragma unroll
    for (int i = 0; i < 2; ++i) {
        const float4 v0 = *reinterpret_cast<const float4*>(x + base + i * 8);
        const float4 v1 = *reinterpret_cast<const float4*>(x + base + i * 8 + 4);
        bf16x8 o;
        o[0] = (short)f2bf(v0.x); o[1] = (short)f2bf(v0.y);
        o[2] = (short)f2bf(v0.z); o[3] = (short)f2bf(v0.w);
        o[4] = (short)f2bf(v1.x); o[5] = (short)f2bf(v1.y);
        o[6] = (short)f2bf(v1.z); o[7] = (short)f2bf(v1.w);
        *reinterpret_cast<bf16x8*>(xb + base + i * 8) = o;
    }
}

// ---------------------------------------------------------------------------
// Kernel 0b: repack W fp32 [1024][256] -> bf16 hi/lo, k-slice-major:
// Wp[wsel][half][kslice=k/8][n][j=k%8].  3 MB total.  Grid (128, 3) x 256.
// ---------------------------------------------------------------------------
__global__ __launch_bounds__(256) void convw_kernel(
    const float* __restrict__ Wq, const float* __restrict__ Wk,
    const float* __restrict__ Wv, ushort_t* __restrict__ Wp)
{
    const int ks   = blockIdx.x;    // 0..127
    const int wsel = blockIdx.y;    // 0..2
    const float* __restrict__ W = (wsel == 0) ? Wq : (wsel == 1) ? Wk : Wv;
    const int n = threadIdx.x;      // 0..255

    bf16x8 hv, lv;
    #pragma unroll
    for (int j = 0; j < 8; ++j) {
        float v = W[(size_t)(ks * 8 + j) * U_ + n];
        ushort_t h = f2bf(v);
        hv[j] = (short)h;
        lv[j] = (short)f2bf(v - bf2f(h));
    }
    size_t base = (size_t)wsel * 524288;   // 2*128*256*8
    *reinterpret_cast<bf16x8*>(&Wp[base + ((size_t)ks) * 2048 + n * 8]) = hv;
    *reinterpret_cast<bf16x8*>(&Wp[base + ((size_t)(128 + ks)) * 2048 + n * 8]) = lv;
}

// ---------------------------------------------------------------------------
// Kernel 1 (R8): projection GEMM, 2-pass MFMA z = xb * (W_hi + W_lo).
// A is PRE-CONVERTED bf16 -> zero VALU on the critical path. BK=32, 32
// K-steps, A+B double-buffered (80 KB LDS -> 2 blocks/CU). 4 waves, each
// 128m x 64n, acc = 4mr x 2nf x f32x16. Per wave per step: 16 ds_read_b128
// (all lane-contiguous, conflict-free) + 32 MFMA. A chunk-major [c][row].
// ---------------------------------------------------------------------------
__global__ __launch_bounds__(256, 2) void proj_mfma_kernel(
    const ushort_t* __restrict__ xb,
    const ushort_t* __restrict__ Wp,
    ushort_t* __restrict__ qh_g, ushort_t* __restrict__ kh_g,
    ushort_t* __restrict__ vth_g)
{
    __shared__ ushort_t As[2][4 * 128 * 8];       // [dbuf][c][row][8]   8 KB/buf
    __shared__ ushort_t Bs[2][2 * 4 * 256 * 8];   // [dbuf][half][ksl][n][8] 32 KB/buf

    // XCD grouping: xcd owns row-tiles xcd*16..+15; 3 wsel blocks of one
    // row-tile are consecutive on the XCD (x tile L2-shared across wsel).
    const int orig = blockIdx.x;            // 0..383
    const int xcd  = orig & 7;
    const int idx  = orig >> 3;             // 0..47
    const int q3   = idx / 3;
    const int wsel = idx - q3 * 3;
    const int row0 = (xcd * 16 + q3) * 128;

    const int tid = threadIdx.x;
    const int l = tid & 63, w = tid >> 6;   // w = n-quarter
    const int m = l & 31, hi = l >> 5;

    const ushort_t* __restrict__ WpB = Wp + (size_t)wsel * 524288;

    f32x16 acc[4][2];
    #pragma unroll
    for (int mr = 0; mr < 4; ++mr)
        #pragma unroll
        for (int nf = 0; nf < 2; ++nf)
            #pragma unroll
            for (int r = 0; r < 16; ++r) acc[mr][nf][r] = 0.f;

    // stage A: 512 chunks = [c][row]; chunk ci: c = ci>>7, r = ci&127
    auto stageA = [&](int buf, int ks) {
        #pragma unroll
        for (int i = 0; i < 2; ++i) {
            int ci = i * 256 + tid;
            int c = ci >> 7, r = ci & 127;
            const ushort_t* src = xb + (size_t)(row0 + r) * F_ + ks * 32 + c * 8;
            gload16(src, (char*)&As[buf][0] + (size_t)(i * 256 + w * 64) * 16);
        }
    };
    // stage B: 2048 chunks = [half][ksl][n]; linear copy of 4 kslices x 2 halves
    auto stageB = [&](int buf, int ks) {
        #pragma unroll
        for (int i = 0; i < 8; ++i) {
            int ci = i * 256 + tid;
            int half = ci >> 10, rem = ci & 1023;
            const ushort_t* src = WpB + (size_t)half * 262144
                                  + (size_t)ks * 8192 + rem * 8;
            gload16(src, (char*)&Bs[buf][0] + (size_t)(i * 256 + w * 64) * 16);
        }
    };

    stageA(0, 0);
    stageB(0, 0);
    __syncthreads();   // implicit vmcnt(0) drain

    for (int ks = 0; ks < 32; ++ks) {
        const int cur = ks & 1;
        if (ks < 31) { stageA(cur ^ 1, ks + 1); stageB(cur ^ 1, ks + 1); }

        const ushort_t* Ac = &As[cur][0];
        const ushort_t* Bc = &Bs[cur][0];

        #pragma unroll
        for (int g = 0; g < 2; ++g) {
            const int ksl = g * 2 + hi;           // kslice 0..3
            bf16x8 ah[4];
            #pragma unroll
            for (int mr = 0; mr < 4; ++mr)
                ah[mr] = *reinterpret_cast<const bf16x8*>(
                    &Ac[(size_t)(ksl * 128 + mr * 32 + m) * 8]);
            #pragma unroll
            for (int nf = 0; nf < 2; ++nf) {
                const int nn = w * 64 + nf * 32 + m;
                const bf16x8 bh = *reinterpret_cast<const bf16x8*>(
                    &Bc[(size_t)(ksl * 2048 + nn * 8)]);
                const bf16x8 bl = *reinterpret_cast<const bf16x8*>(
                    &Bc[(size_t)(8192 + ksl * 2048 + nn * 8)]);
                #pragma unroll
                for (int mr = 0; mr < 4; ++mr) {
                    acc[mr][nf] = __builtin_amdgcn_mfma_f32_32x32x16_bf16(ah[mr], bh, acc[mr][nf], 0, 0, 0);
                    acc[mr][nf] = __builtin_amdgcn_mfma_f32_32x32x16_bf16(ah[mr], bl, acc[mr][nf], 0, 0, 0);
                }
            }
        }
        __syncthreads();   // next-buf staged, cur-buf reads done
    }

    // ---- epilogue: tanh, round to bf16, store (hi only) ----
    // C layout (32x32): col = lane&31, row = (reg&3) + 8*(reg>>2) + 4*(lane>>5)
    #pragma unroll
    for (int mr = 0; mr < 4; ++mr) {
        const int row_base = row0 + mr * 32;
        if (wsel < 2) {
            ushort_t* __restrict__ hp = (wsel == 0) ? qh_g : kh_g;
            #pragma unroll
            for (int nf = 0; nf < 2; ++nf) {
                const int u = w * 64 + nf * 32 + m;
                #pragma unroll
                for (int reg = 0; reg < 16; ++reg) {
                    const int rl = (reg & 3) + 8 * (reg >> 2) + 4 * hi;
                    hp[(size_t)(row_base + rl) * U_ + u] =
                        f2bf(tanhf(acc[mr][nf][reg]));
                }
            }
        } else {
            const int b     = row0 >> 11;    // row-tiles never straddle batches
            const int s_blk = (row0 & 2047) + mr * 32;
            #pragma unroll
            for (int nf = 0; nf < 2; ++nf) {
                const int u = w * 64 + nf * 32 + m;
                #pragma unroll
                for (int rg = 0; rg < 4; ++rg) {
                    ushort4 hv;
                    hv.x = f2bf(tanhf(acc[mr][nf][rg * 4 + 0]));
                    hv.y = f2bf(tanhf(acc[mr][nf][rg * 4 + 1]));
                    hv.z = f2bf(tanhf(acc[mr][nf][rg * 4 + 2]));
                    hv.w = f2bf(tanhf(acc[mr][nf][rg * 4 + 3]));
                    size_t off = ((size_t)b * U_ + u) * S_ + s_blk + 8 * rg + 4 * hi;
                    *reinterpret_cast<ushort4*>(&vth_g[off]) = hv;
                }
            }
        }
    }
}

// ---------------------------------------------------------------------------
// Kernel 2: flash attention, plain bf16 MFMA, SPLIT-K x2. (unchanged R5)
// ---------------------------------------------------------------------------
__global__ __launch_bounds__(256, 2) void attn_mfma_kernel(
    const ushort_t* __restrict__ qh_g,
    const ushort_t* __restrict__ kh_g,
    const ushort_t* __restrict__ vth_g,
    float* __restrict__ O0, float* __restrict__ O1,
    float* __restrict__ ml)
{
    __shared__ ushort_t Kbuf[2][32 * 256];   // [dbuf][key][u] swizzled (32 KB)
    __shared__ ushort_t Vbuf[2][256 * 40];   // [dbuf][u][32+8pad]     (40 KB)
    __shared__ ushort_t Pbuf[4][512];        // [wave][kg][q][8]        (4 KB)

    const int tid = threadIdx.x;
    const int l  = tid & 63, w = tid >> 6;
    const int kq = l & 15,  g = l >> 4;

    // XCD swizzle: each XCD owns one batch (64 blocks: 32 q-tiles x 2 halves)
    const int logical = (blockIdx.x & 7) * 64 + (blockIdx.x >> 3);
    const int b     = logical >> 6;
    const int qb    = (logical >> 1) & 31;
    const int khalf = logical & 1;
    const int qrow0 = b * S_ + qb * 64 + w * 16;
    const int kb0   = khalf * 1024;           // key offset within batch

    // preload Q fragments (B-operand: n = lane&15 -> q, k = u = g*8+j)
    bf16x8 qh[8];
    {
        const ushort_t* qbh = qh_g + (size_t)(qrow0 + kq) * U_;
        #pragma unroll
        for (int us = 0; us < 8; ++us)
            qh[us] = *reinterpret_cast<const bf16x8*>(qbh + us * 32 + g * 8);
    }

    f32x4 O[16];
    #pragma unroll
    for (int nt = 0; nt < 16; ++nt) O[nt] = zero4();
    float m_run = -INFINITY, l_run = 0.f;

    auto stage = [&](int buf, int k0) {
        #pragma unroll
        for (int i = 0; i < 4; ++i) {
            int c = w * 256 + i * 64 + l;
            int key = c >> 5, uc = c & 31;
            int ucs = uc ^ (key & 7);                       // pre-swizzled source
            size_t so = (size_t)(b * S_ + k0 + key) * U_ + ucs * 8;
            gload16(kh_g + so, &Kbuf[buf][(w * 256 + i * 64) * 8]);
        }
        #pragma unroll
        for (int i = 0; i < 5; ++i) {
            int c = w * 320 + i * 64 + l;
            int u = (c * 52429) >> 18;                      // c / 5
            int kc = c - u * 5;
            size_t so = ((size_t)b * U_ + u) * S_ + k0 + kc * 8;
            const ushort_t* sh = (kc < 4) ? (vth_g + so) : vth_g;
            gload16(sh, &Vbuf[buf][(w * 320 + i * 64) * 8]);
        }
    };

    stage(0, kb0);
    asm volatile("s_waitcnt vmcnt(0)" ::: "memory");
    __builtin_amdgcn_s_barrier();

    const float scale = 0.03125f;   // 1/sqrt(F=1024)

    for (int t = 0; t < 32; ++t) {
        const int cur = t & 1;
        if (t < 31) stage(cur ^ 1, kb0 + (t + 1) * 32);

        const ushort_t* Kh = Kbuf[cur];
        const ushort_t* Vh = Vbuf[cur];

        // ---- QK^T as S^T = K * Q^T ----
        f32x4 hh0 = zero4(), hh1 = zero4();
        #pragma unroll
        for (int us = 0; us < 8; ++us) {
            int off0 = kq * 256 + ((us * 32 + g * 8) ^ ((kq & 7) * 8));
            bf16x8 k0h = *reinterpret_cast<const bf16x8*>(Kh + off0);
            hh0 = __builtin_amdgcn_mfma_f32_16x16x32_bf16(k0h, qh[us], hh0, 0, 0, 0);
            int off1 = off0 + 16 * 256;                     // key+16
            bf16x8 k1h = *reinterpret_cast<const bf16x8*>(Kh + off1);
            hh1 = __builtin_amdgcn_mfma_f32_16x16x32_bf16(k1h, qh[us], hh1, 0, 0, 0);
        }
        f32x4 s0 = hh0 * scale;   // keys g*4+r,    q = kq
        f32x4 s1 = hh1 * scale;   // keys 16+g*4+r, q = kq

        // ---- online softmax (per q = lane&15) ----
        float tm = fmaxf(fmaxf(fmaxf(s0[0], s0[1]), fmaxf(s0[2], s0[3])),
                         fmaxf(fmaxf(s1[0], s1[1]), fmaxf(s1[2], s1[3])));
        tm = fmaxf(tm, __shfl_xor(tm, 16));
        tm = fmaxf(tm, __shfl_xor(tm, 32));
        float mn = fmaxf(m_run, tm);
        ushort_t ph0[4], ph1[4];
        float su = 0.f;
        #pragma unroll
        for (int r = 0; r < 4; ++r) {
            ph0[r] = f2bf(expf(s0[r] - mn)); su += bf2f(ph0[r]);
        }
        #pragma unroll
        for (int r = 0; r < 4; ++r) {
            ph1[r] = f2bf(expf(s1[r] - mn)); su += bf2f(ph1[r]);
        }
        su += __shfl_xor(su, 16);
        su += __shfl_xor(su, 32);
        float f = expf(m_run - mn);             // first tile: exp(-inf) = 0
        l_run = l_run * f + su;
        m_run = mn;

        // ---- write P into PV-A-fragment layout [kg][q][8] ----
        {
            ushort4 a, c;
            a.x = ph0[0]; a.y = ph0[1]; a.z = ph0[2]; a.w = ph0[3];
            c.x = ph1[0]; c.y = ph1[1]; c.z = ph1[2]; c.w = ph1[3];
            int pw0 = ((g >> 1)) * 128 + kq * 8 + (g & 1) * 4;        // kg 0|1
            int pw1 = (2 + (g >> 1)) * 128 + kq * 8 + (g & 1) * 4;    // kg 2|3
            *reinterpret_cast<ushort4*>(&Pbuf[w][pw0]) = a;
            *reinterpret_cast<ushort4*>(&Pbuf[w][pw1]) = c;
        }

        // ---- rescale O (rows of C-layout are q = g*4+r) ----
        float fr0 = __shfl(f, g * 4 + 0), fr1 = __shfl(f, g * 4 + 1);
        float fr2 = __shfl(f, g * 4 + 2), fr3 = __shfl(f, g * 4 + 3);
        #pragma unroll
        for (int nt = 0; nt < 16; ++nt) {
            O[nt][0] *= fr0; O[nt][1] *= fr1; O[nt][2] *= fr2; O[nt][3] *= fr3;
        }

        // ---- PV: O += P * V ----
        bf16x8 pa_h = *reinterpret_cast<const bf16x8*>(&Pbuf[w][g * 128 + kq * 8]);
        #pragma unroll
        for (int nt = 0; nt < 16; ++nt) {
            int vo = (nt * 16 + kq) * 40 + g * 8;
            bf16x8 vh = *reinterpret_cast<const bf16x8*>(Vh + vo);
            O[nt] = __builtin_amdgcn_mfma_f32_16x16x32_bf16(pa_h, vh, O[nt], 0, 0, 0);
        }

        asm volatile("s_waitcnt vmcnt(0)" ::: "memory");
        __builtin_amdgcn_s_barrier();
    }

    // ---- epilogue: store UNNORMALIZED O + (m, l) per row ----
    float* __restrict__ Op = khalf ? O1 : O0;
    #pragma unroll
    for (int nt = 0; nt < 16; ++nt) {
        const int col = nt * 16 + kq;
        Op[(size_t)(qrow0 + g * 4 + 0) * U_ + col] = O[nt][0];
        Op[(size_t)(qrow0 + g * 4 + 1) * U_ + col] = O[nt][1];
        Op[(size_t)(qrow0 + g * 4 + 2) * U_ + col] = O[nt][2];
        Op[(size_t)(qrow0 + g * 4 + 3) * U_ + col] = O[nt][3];
    }
    if (g == 0) {   // lanes 0..15: one per q-row of this wave
        ml[((size_t)khalf * M_ + qrow0 + kq) * 2 + 0] = m_run;
        ml[((size_t)khalf * M_ + qrow0 + kq) * 2 + 1] = l_run;
    }
}

// ---------------------------------------------------------------------------
// Kernel 3: merge the two split-K partials. (unchanged R5)
// ---------------------------------------------------------------------------
__global__ __launch_bounds__(256) void merge_kernel(
    const float* __restrict__ O1, const float* __restrict__ ml,
    float* __restrict__ out)
{
    const int tid = threadIdx.x;
    const int row = blockIdx.x * 4 + (tid >> 6);
    const int c   = (tid & 63) * 4;

    const float m0 = ml[(size_t)row * 2 + 0];
    const float l0 = ml[(size_t)row * 2 + 1];
    const float m1 = ml[((size_t)M_ + row) * 2 + 0];
    const float l1 = ml[((size_t)M_ + row) * 2 + 1];
    const float Mx = fmaxf(m0, m1);
    float a0 = expf(m0 - Mx), a1 = expf(m1 - Mx);
    const float inv = 1.f / (a0 * l0 + a1 * l1);
    a0 *= inv; a1 *= inv;

    const size_t off = (size_t)row * U_ + c;
    const float4 o0 = *reinterpret_cast<const float4*>(out + off);
    const float4 o1 = *reinterpret_cast<const float4*>(O1 + off);
    float4 r;
    r.x = o0.x * a0 + o1.x * a1;
    r.y = o0.y * a0 + o1.y * a1;
    r.z = o0.z * a0 + o1.z * a1;
    r.w = o0.w * a0 + o1.w * a1;
    *reinterpret_cast<float4*>(out + off) = r;
}

extern "C" void kernel_launch(void* const* d_in, const int* in_sizes, int n_in,
                              void* d_out, int out_size, void* d_ws, size_t ws_size,
                              hipStream_t stream)
{
    (void)in_sizes; (void)n_in; (void)out_size; (void)ws_size;
    const float* x  = (const float*)d_in[0];
    const float* Wq = (const float*)d_in[1];
    const float* Wk = (const float*)d_in[2];
    const float* Wv = (const float*)d_in[3];
    float* out = (float*)d_out;

    ushort_t* ws = (ushort_t*)d_ws;
    const size_t T = (size_t)M_ * U_;        // 4,194,304 elements
    ushort_t* qh_g  = ws;                    //  8 MiB
    ushort_t* kh_g  = ws + T;                //  8 MiB
    ushort_t* vth_g = ws + 2 * T;            //  8 MiB  [B][U][S]
    ushort_t* Wp    = ws + 3 * T;            //  3 MiB  [3][2][128][256][8]
    ushort_t* xb    = ws + 3 * T + 1572864;  // 32 MiB bf16 x  (dead after proj)
    // O1/ml OVERLAY xb: written by attn only after proj has consumed xb.
    float*    O1    = (float*)xb;            // 16.8 MiB partial
    float*    ml    = O1 + T;                // 0.26 MiB [2][M][2]

    convx_kernel<<<dim3(4096), 256, 0, stream>>>(x, xb);
    convw_kernel<<<dim3(128, 3), 256, 0, stream>>>(Wq, Wk, Wv, Wp);

    proj_mfma_kernel<<<dim3(384), 256, 0, stream>>>(
        xb, Wp, qh_g, kh_g, vth_g);

    attn_mfma_kernel<<<dim3(512), 256, 0, stream>>>(
        qh_g, kh_g, vth_g, out, O1, ml);

    merge_kernel<<<dim3(M_ / 4), 256, 0, stream>>>(O1, ml, out);
}